// Round 1
// baseline (747.889 us; speedup 1.0000x reference)
//
#include <hip/hip_runtime.h>
#include <hip/hip_bf16.h>
#include <math.h>

// skip-gram hierarchical-softmax loss.
// Per pair b: dot = <W0[target[b]], W1[context[b]]>  (D=128)
// loss += -sum_{j<len[b]} log_sigmoid((1-2*codes[b][j]) * dot)
//       = -( n_pos*logsig(dot) + n_neg*logsig(-dot) ),  n_neg = #(code==1 & valid)
//
// Kernel 1: one wave (64 lanes) per pair. float2 per lane covers D=128.
// Block = 256 threads = 4 pairs; per-block partial sum -> d_ws.
// Kernel 2: single block reduces the partials into d_out[0].

#define D 128
#define LMAX 20
#define WAVES_PER_BLOCK 4
#define BLOCK_THREADS (WAVES_PER_BLOCK * 64)

__device__ __forceinline__ float log_sigmoid(float x) {
    // stable: log(sigma(x)) = min(x,0) - log1p(exp(-|x|))
    return fminf(x, 0.0f) - log1pf(__expf(-fabsf(x)));
}

__global__ __launch_bounds__(BLOCK_THREADS) void pair_loss_kernel(
    const float* __restrict__ W0, const float* __restrict__ W1,
    const int* __restrict__ target, const int* __restrict__ context,
    const int* __restrict__ codes, const int* __restrict__ lengths,
    float* __restrict__ partials, int B) {

    const int lane = threadIdx.x & 63;
    const int wave = threadIdx.x >> 6;
    const int pair = blockIdx.x * WAVES_PER_BLOCK + wave;

    float contrib = 0.0f;
    if (pair < B) {
        const int t = target[pair];
        const int c = context[pair];
        const float2* r0 = (const float2*)(W0 + (size_t)t * D);
        const float2* r1 = (const float2*)(W1 + (size_t)c * D);
        const float2 a = r0[lane];
        const float2 b = r1[lane];
        float d = a.x * b.x + a.y * b.y;
        #pragma unroll
        for (int off = 32; off; off >>= 1)
            d += __shfl_down(d, off, 64);
        d = __shfl(d, 0, 64);  // broadcast dot to all lanes

        const int len = lengths[pair];
        int code = 0;
        if (lane < len) code = codes[pair * LMAX + lane];
        const unsigned long long negmask = __ballot(lane < len && code == 1);
        const int n_neg = __popcll(negmask);
        const int n_pos = len - n_neg;

        if (lane == 0) {
            const float lsp = log_sigmoid(d);
            const float lsn = log_sigmoid(-d);
            contrib = -((float)n_pos * lsp + (float)n_neg * lsn);
        }
    }

    __shared__ float smem[WAVES_PER_BLOCK];
    if (lane == 0) smem[wave] = contrib;
    __syncthreads();
    if (threadIdx.x == 0) {
        float s = 0.0f;
        #pragma unroll
        for (int i = 0; i < WAVES_PER_BLOCK; ++i) s += smem[i];
        partials[blockIdx.x] = s;
    }
}

__global__ __launch_bounds__(256) void reduce_kernel(
    const float* __restrict__ partials, int n, float* __restrict__ out) {
    float s = 0.0f;
    for (int i = threadIdx.x; i < n; i += 256) s += partials[i];
    #pragma unroll
    for (int off = 32; off; off >>= 1)
        s += __shfl_down(s, off, 64);
    __shared__ float smem[4];
    const int lane = threadIdx.x & 63;
    const int wave = threadIdx.x >> 6;
    if (lane == 0) smem[wave] = s;
    __syncthreads();
    if (threadIdx.x == 0) {
        float t = 0.0f;
        #pragma unroll
        for (int i = 0; i < 4; ++i) t += smem[i];
        out[0] = t;
    }
}

extern "C" void kernel_launch(void* const* d_in, const int* in_sizes, int n_in,
                              void* d_out, int out_size, void* d_ws, size_t ws_size,
                              hipStream_t stream) {
    const float* W0      = (const float*)d_in[0];
    const float* W1      = (const float*)d_in[1];
    const int*   target  = (const int*)d_in[2];
    const int*   context = (const int*)d_in[3];
    const int*   codes   = (const int*)d_in[4];
    const int*   lengths = (const int*)d_in[5];
    float* out = (float*)d_out;

    const int B = in_sizes[2];                       // 16384
    const int grid = (B + WAVES_PER_BLOCK - 1) / WAVES_PER_BLOCK;  // 4096
    float* partials = (float*)d_ws;

    pair_loss_kernel<<<grid, BLOCK_THREADS, 0, stream>>>(
        W0, W1, target, context, codes, lengths, partials, B);
    reduce_kernel<<<1, 256, 0, stream>>>(partials, grid, out);
}